// Round 7
// baseline (50.012 us; speedup 1.0000x reference)
//
#include <hip/hip_runtime.h>
#include <hip/hip_bf16.h>

#define N_ 8192
#define D_ 256
#define BM 128
#define NB (N_ / BM)            // 64
#define NT (NB * (NB + 1) / 2)  // 2080 triangular tiles

typedef float f32x4 __attribute__((ext_vector_type(4)));

// ws layout (doubles): [0..95] = 32 slots x {pos_cnt, pos_sim_sum, neg_sim_sum}
//                      [128..2175] = 512 lastrow wave-slots x {lp_s, lp_c, ln_s, ln_c}
// Xb (fp8, permuted layout) at byte offset 32768, 2 MB.
//
// Xb row layout (256 B per row): element k (s=k>>5 step, sl=(k>>3)&3 slice, b=k&7)
// lives at byte chunk ((sl*4 + s/2) ^ (row&7))*16 + (s&1)*8 + b. This makes the
// MFMA fragment read a single swizzled ds_read_b128 covering 2 K-steps.

// ---------------- prep: f32 -> fp8 permuted convert + fp64 lastrow ----------------
__global__ void prep_kernel(const float* __restrict__ X, const int* __restrict__ tg,
                            unsigned char* __restrict__ Xb, double* __restrict__ accd) {
  if (blockIdx.x < 2048) {
    if (blockIdx.x == 0 && threadIdx.x < 96) accd[threadIdx.x] = 0.0;
    int i = blockIdx.x * 256 + threadIdx.x;  // float4 index, exactly 524288
    float4 v = ((const float4*)X)[i];
    int r = i >> 6;            // row
    int k0 = (i & 63) * 4;     // first element within row
    int pk = __builtin_amdgcn_cvt_pk_fp8_f32(v.x, v.y, 0, false);
    pk = __builtin_amdgcn_cvt_pk_fp8_f32(v.z, v.w, pk, true);  // bytes [x,y,z,w]
    int s = k0 >> 5, sl = (k0 >> 3) & 3, b = k0 & 7;
    int perm = sl * 64 + s * 8 + b;            // 4 consecutive bytes, 4-aligned
    int chunk = (perm >> 4) ^ (r & 7);         // XOR bank swizzle at 16B grain
    *(unsigned int*)(Xb + (size_t)r * 256 + chunk * 16 + (perm & 15)) = (unsigned int)pk;
  } else {
    // ---- last-row stats in fp64 (proven absmax-0 path), race-free slots ----
    int lb = blockIdx.x - 2048;  // 0..127
    int lane = threadIdx.x & 63, wv = threadIdx.x >> 6;
    const float4* xl = (const float4*)(X + (size_t)(N_ - 1) * D_);
    float4 a = xl[lane];  // lane covers k = lane*4 .. +4
    int tlast = tg[N_ - 1];
    double lp = 0, lpc = 0, ln = 0, lnc = 0;
    for (int cc = 0; cc < 16; ++cc) {
      int j = lb * 64 + wv * 16 + cc;
      float4 bq = ((const float4*)(X + (size_t)j * D_))[lane];
      double s = (double)a.x * bq.x + (double)a.y * bq.y +
                 (double)a.z * bq.z + (double)a.w * bq.w;
#pragma unroll
      for (int off = 32; off; off >>= 1) s += __shfl_down(s, off);
      if (lane == 0) {
        float sf = (float)s;  // round to f32, then f32 comparisons like reference
        bool same = (tg[j] == tlast);
        if (same && sf < 1.0f) { lp += sf; lpc += 1.0; }
        if (!same) { ln += sf; lnc += 1.0; }
      }
    }
    if (lane == 0) {
      double* slot = accd + 128 + (size_t)(lb * 4 + wv) * 4;
      slot[0] = lp; slot[1] = lpc; slot[2] = ln; slot[3] = lnc;
    }
  }
}

// ---------------- fused fp8 GEMM + masked reduction ----------------
// Whole-K resident: stage A(32KB)+B(32KB) once, ONE barrier, barrier-free MFMA loop.
__global__ __launch_bounds__(256, 2) void simloss_kernel(
    const unsigned char* __restrict__ Xb, const int* __restrict__ tg,
    double* __restrict__ accd) {
  __shared__ __align__(16) char lds[65536];  // A at 0, B at 32768
  __shared__ float red[12];

  // ---- triangular tile decode ----
  const int t = blockIdx.x;
  int bi = (int)(((2.0f * NB + 1.0f) -
                  sqrtf((2.0f * NB + 1.0f) * (2.0f * NB + 1.0f) - 8.0f * (float)t)) * 0.5f);
  if (bi < 0) bi = 0;
  if (bi > NB - 1) bi = NB - 1;
  while (((bi + 1) * NB - ((bi + 1) * bi) / 2) <= t) ++bi;
  while ((bi * NB - (bi * (bi - 1)) / 2) > t) --bi;
  const int bj = bi + (t - (bi * NB - (bi * (bi - 1)) / 2));

  const int tid = threadIdx.x;
  const int lane = tid & 63, wv = tid >> 6;
  const int wr = wv >> 1, wc = wv & 1;  // wave -> 64x64 sub-tile
  const int rowA0 = bi * BM, rowB0 = bj * BM;

#define GLDS(g, l) \
  __builtin_amdgcn_global_load_lds((const __attribute__((address_space(1))) void*)(g), \
                                   (__attribute__((address_space(3))) void*)(l), 16, 0, 0)
  // stage both full tiles: 2048 16B chunks each; Xb rows copied linearly
  const unsigned char* gA = Xb + (size_t)rowA0 * 256;
  const unsigned char* gB = Xb + (size_t)rowB0 * 256;
#pragma unroll
  for (int q = 0; q < 8; ++q) {
    int c = (q * 4 + wv) * 64 + lane;                  // chunk index
    GLDS(gA + c * 16, lds + (q * 4 + wv) * 1024);      // wave-uniform dest base
    GLDS(gB + c * 16, lds + 32768 + (q * 4 + wv) * 1024);
  }
  __syncthreads();  // single drain+barrier of the whole kernel
#undef GLDS

  // ---- barrier-free MFMA loop: 32 swizzled ds_read_b128 + 128 fp8 MFMA ----
  const int fr = lane & 15, sl = lane >> 4;
  const int g = fr & 7;  // row&7 for all this lane's fragment rows
  const char* Abase = lds + (wr * 64 + fr) * 256;
  const char* Bbase = lds + 32768 + (wc * 64 + fr) * 256;

  f32x4 acc[4][4] = {};
  union U { int4 v; long l[2]; };
#pragma unroll
  for (int p = 0; p < 4; ++p) {  // step-pair: covers K-steps 2p, 2p+1
    const int ch = ((sl * 4 + p) ^ g) * 16;
    U a[4], b[4];
#pragma unroll
    for (int m = 0; m < 4; ++m) a[m].v = *(const int4*)(Abase + m * 4096 + ch);
#pragma unroll
    for (int n = 0; n < 4; ++n) b[n].v = *(const int4*)(Bbase + n * 4096 + ch);
#pragma unroll
    for (int m = 0; m < 4; ++m)
#pragma unroll
      for (int n = 0; n < 4; ++n) {
        acc[m][n] = __builtin_amdgcn_mfma_f32_16x16x32_fp8_fp8(a[m].l[0], b[n].l[0],
                                                               acc[m][n], 0, 0, 0);
        acc[m][n] = __builtin_amdgcn_mfma_f32_16x16x32_fp8_fp8(a[m].l[1], b[n].l[1],
                                                               acc[m][n], 0, 0, 0);
      }
  }

  // ---- epilogue: C/D layout col=lane&15, row=(lane>>4)*4+reg (dtype-indep) ----
  const int cRow = sl * 4, cCol = fr;
  int tj[4], ti[4][4];
#pragma unroll
  for (int n = 0; n < 4; ++n) tj[n] = tg[rowB0 + wc * 64 + n * 16 + cCol];
#pragma unroll
  for (int m = 0; m < 4; ++m)
#pragma unroll
    for (int r = 0; r < 4; ++r) ti[m][r] = tg[rowA0 + wr * 64 + m * 16 + cRow + r];

  float pc = 0.f, ps = 0.f, ns = 0.f;
#pragma unroll
  for (int m = 0; m < 4; ++m)
#pragma unroll
    for (int n = 0; n < 4; ++n)
#pragma unroll
      for (int r = 0; r < 4; ++r) {
        float s = acc[m][n][r];
        bool same = (ti[m][r] == tj[n]);
        if (same & (s < 0.9f)) { pc += 1.0f; ps += s; }
        if ((!same) & (s > 0.5f)) { ns += s; }
      }

  // ---- block reduction + per-slot atomics ----
#pragma unroll
  for (int off = 32; off > 0; off >>= 1) {
    pc += __shfl_down(pc, off);
    ps += __shfl_down(ps, off);
    ns += __shfl_down(ns, off);
  }
  if (lane == 0) { red[0 + wv] = pc; red[4 + wv] = ps; red[8 + wv] = ns; }
  __syncthreads();
  if (tid == 0) {
    double w = (bi == bj) ? 1.0 : 2.0;  // off-diagonal tiles count twice
    double* slot = accd + (blockIdx.x & 31) * 3;
    atomicAdd(&slot[0], w * (double)(red[0] + red[1] + red[2] + red[3]));
    atomicAdd(&slot[1], w * (double)(red[4] + red[5] + red[6] + red[7]));
    atomicAdd(&slot[2], w * (double)(red[8] + red[9] + red[10] + red[11]));
  }
}

// ---------------- finalize (single wave) ----------------
__global__ void finalize_kernel(const double* __restrict__ accd, float* __restrict__ out) {
  int l = threadIdx.x;  // 64 threads
  double lp = 0, lpc = 0, ln = 0, lnc = 0;
  for (int q = l; q < 512; q += 64) {
    const double* s = accd + 128 + (size_t)q * 4;
    lp += s[0]; lpc += s[1]; ln += s[2]; lnc += s[3];
  }
  double pc = 0, ps = 0, ns = 0;
  if (l < 32) { pc = accd[l * 3]; ps = accd[l * 3 + 1]; ns = accd[l * 3 + 2]; }
#pragma unroll
  for (int off = 32; off > 0; off >>= 1) {
    lp += __shfl_down(lp, off);  lpc += __shfl_down(lpc, off);
    ln += __shfl_down(ln, off);  lnc += __shfl_down(lnc, off);
    pc += __shfl_down(pc, off);  ps += __shfl_down(ps, off);
    ns += __shfl_down(ns, off);
  }
  if (l == 0) {
    out[0] = (float)((pc - ps + ns) / (double)N_);
    out[1] = 0.0f;  // prec: reference never increments c
    out[2] = (float)(lp / fmax(lpc, 1.0));
    out[3] = (float)(ln / fmax(lnc, 1.0));
  }
}

extern "C" void kernel_launch(void* const* d_in, const int* in_sizes, int n_in,
                              void* d_out, int out_size, void* d_ws, size_t ws_size,
                              hipStream_t stream) {
  const float* X = (const float*)d_in[0];
  const int* tg = (const int*)d_in[1];
  float* out = (float*)d_out;
  double* accd = (double*)d_ws;
  unsigned char* Xb = (unsigned char*)d_ws + 32768;

  prep_kernel<<<2048 + 128, 256, 0, stream>>>(X, tg, Xb, accd);
  simloss_kernel<<<NT, 256, 0, stream>>>(Xb, tg, accd);
  finalize_kernel<<<1, 64, 0, stream>>>(accd, out);
}